// Round 7
// baseline (36.412 us; speedup 1.0000x reference)
//
#include <hip/hip_runtime.h>
#include <math.h>

#define NEXP 8
#define DIM 1024
#define NTOK 32768            // B*S = 8*4096
#define EPSF 1e-9f

#define K1_NB 1024            // 1024 blocks x 4 waves x 8 tokens = 32768
                              // = exactly 4 blocks/CU x 256 CUs, one round

// ---------------------------------------------------------------------------
// Fused kernel: GEMV + gumbel/softmax/top-2 + loss partials, one pass over x.
// W (32 KB) staged in LDS once per block. Each wave: 2 iterations of a
// 4-token GEMV: per p-chunk, prefetch the next 4 x-loads, read 8 W float4
// from LDS (32 ds_read_b128 per 4 tokens = 8/token, half of R6), accumulate
// acc[4][8]. Live VGPRs ~110 under the __launch_bounds__(256,4) cap of 128
// -> 4 blocks/CU, 16 waves/CU. Split butterfly (proven in R3 for 4 tokens)
// leaves lane l with logit(expert l&7); lanes 0..31 park 4x8 logits in zlds.
// After a barrier, lanes 0..7 each own one token: epilogue fully in registers
// (identical math to the proven K2), write the 9-float mask row, park 16
// loss stats in slds; block reduce -> partials[block][16].
// ---------------------------------------------------------------------------
__global__ __launch_bounds__(256, 4) void fused_kernel(
    const float* __restrict__ x, const float* __restrict__ W,
    const float* __restrict__ noise, float* __restrict__ out,
    float* __restrict__ partials)
{
    __shared__ float4 Wlds[NEXP * DIM / 4];   // 2048 float4 = 32 KB
    __shared__ float  zlds[4][8][8];          // per-wave token-major logits, 1 KB
    __shared__ float  slds[4][8][16];         // per-token loss stats, 2 KB

    const int tid  = threadIdx.x;
    const int lane = tid & 63;
    const int wid  = tid >> 6;

    const float4* Wg = (const float4*)W;
    #pragma unroll
    for (int i = 0; i < (NEXP * DIM / 4) / 256; ++i)
        Wlds[tid + i * 256] = Wg[tid + i * 256];
    __syncthreads();

    const int gw = (blockIdx.x << 2) + wid;   // wave id 0..4095
    const int t0 = gw << 3;                   // 8 tokens per wave

    const bool p0 = lane & 1;
    const bool p1 = (lane >> 1) & 1;
    const bool p2 = (lane >> 2) & 1;

    #pragma unroll
    for (int h = 0; h < 2; ++h) {
        const int ta = t0 + h * 4;

        // chunk-0 loads for 4 tokens
        float4 xc[4], xn[4];
        #pragma unroll
        for (int j = 0; j < 4; ++j)
            xc[j] = *(const float4*)(x + (size_t)(ta + j) * DIM + (lane << 2));

        float acc[4][NEXP];
        #pragma unroll
        for (int j = 0; j < 4; ++j)
            #pragma unroll
            for (int e = 0; e < NEXP; ++e) acc[j][e] = 0.f;

        #pragma unroll
        for (int p = 0; p < 4; ++p) {
            // prefetch next chunk while consuming current
            if (p < 3) {
                #pragma unroll
                for (int j = 0; j < 4; ++j)
                    xn[j] = *(const float4*)(x + (size_t)(ta + j) * DIM
                                             + (p + 1) * 256 + (lane << 2));
            }
            #pragma unroll
            for (int e = 0; e < NEXP; ++e) {
                float4 wv = Wlds[e * 256 + p * 64 + lane];
                #pragma unroll
                for (int j = 0; j < 4; ++j)
                    acc[j][e] += xc[j].x * wv.x + xc[j].y * wv.y
                               + xc[j].z * wv.z + xc[j].w * wv.w;
            }
            if (p < 3) {
                #pragma unroll
                for (int j = 0; j < 4; ++j) xc[j] = xn[j];
            }
        }

        // split butterfly: 8 partials -> lane owns expert (lane&7)
        float k4[4][4];
        #pragma unroll
        for (int j = 0; j < 4; ++j)
            #pragma unroll
            for (int k = 0; k < 4; ++k) {
                float a = acc[j][2 * k], b = acc[j][2 * k + 1];
                float keep = p0 ? b : a, give = p0 ? a : b;
                k4[j][k] = keep + __shfl_xor(give, 1);
            }
        float k2v[4][2];
        #pragma unroll
        for (int j = 0; j < 4; ++j)
            #pragma unroll
            for (int k = 0; k < 2; ++k) {
                float a = k4[j][2 * k], b = k4[j][2 * k + 1];
                float keep = p1 ? b : a, give = p1 ? a : b;
                k2v[j][k] = keep + __shfl_xor(give, 2);
            }
        float z[4];
        #pragma unroll
        for (int j = 0; j < 4; ++j) {
            float a = k2v[j][0], b = k2v[j][1];
            float keep = p2 ? b : a, give = p2 ? a : b;
            z[j] = keep + __shfl_xor(give, 4);
        }
        #pragma unroll
        for (int j = 0; j < 4; ++j) {
            z[j] += __shfl_xor(z[j], 8);
            z[j] += __shfl_xor(z[j], 16);
            z[j] += __shfl_xor(z[j], 32);
        }

        if (lane < 32) {
            int j = lane >> 3, e = lane & 7;
            float zz = (j == 0) ? z[0] : (j == 1) ? z[1] : (j == 2) ? z[2] : z[3];
            zlds[wid][h * 4 + j][e] = zz;
        }
    }

    __syncthreads();   // zlds visible (also separates LDS phases)

    // ---- epilogue: lane j < 8 owns token t0+j, all math in registers ----
    if (lane < 8) {
        const int t = t0 + lane;

        float4 za = *(const float4*)&zlds[wid][lane][0];
        float4 zb = *(const float4*)&zlds[wid][lane][4];
        float zt[NEXP] = {za.x, za.y, za.z, za.w, zb.x, zb.y, zb.z, zb.w};

        float4 n0 = *(const float4*)(noise + (size_t)t * NEXP);
        float4 n1 = *(const float4*)(noise + (size_t)t * NEXP + 4);
        float nv[NEXP] = {n0.x, n0.y, n0.z, n0.w, n1.x, n1.y, n1.z, n1.w};

        #pragma unroll
        for (int e = 0; e < NEXP; ++e)
            zt[e] += -logf(-logf(nv[e] + EPSF) + EPSF);

        float m = zt[0];
        #pragma unroll
        for (int e = 1; e < NEXP; ++e) m = fmaxf(m, zt[e]);

        float sc[NEXP], s = 0.f;
        #pragma unroll
        for (int e = 0; e < NEXP; ++e) { sc[e] = expf(zt[e] - m); s += sc[e]; }
        float inv = 1.0f / s;
        #pragma unroll
        for (int e = 0; e < NEXP; ++e) sc[e] *= inv;

        // top-2 scan (value desc, earliest index wins ties — matches lax.top_k)
        float b1v = sc[0]; int b1i = 0;
        float b2v = -1.f;  int b2i = -1;
        #pragma unroll
        for (int e = 1; e < NEXP; ++e) {
            if (sc[e] > b1v)      { b2v = b1v; b2i = b1i; b1v = sc[e]; b1i = e; }
            else if (sc[e] > b2v) { b2v = sc[e]; b2i = e; }
        }

        out[(size_t)t * 9] = 1.0f;
        #pragma unroll
        for (int e = 0; e < NEXP; ++e)
            out[(size_t)t * 9 + 1 + e] = (e == b1i) ? b1v : (e == b2i) ? b2v : 0.f;

        // loss stats for this token: [0..7] = sc, [8..15] = sc^2
        *(float4*)&slds[wid][lane][0]  = make_float4(sc[0], sc[1], sc[2], sc[3]);
        *(float4*)&slds[wid][lane][4]  = make_float4(sc[4], sc[5], sc[6], sc[7]);
        *(float4*)&slds[wid][lane][8]  = make_float4(sc[0]*sc[0], sc[1]*sc[1], sc[2]*sc[2], sc[3]*sc[3]);
        *(float4*)&slds[wid][lane][12] = make_float4(sc[4]*sc[4], sc[5]*sc[5], sc[6]*sc[6], sc[7]*sc[7]);
    }

    __syncthreads();
    if (tid < 16) {
        float s = 0.f;
        #pragma unroll
        for (int w = 0; w < 4; ++w)
            #pragma unroll
            for (int j = 0; j < 8; ++j)
                s += slds[w][j][tid];
        partials[blockIdx.x * 16 + tid] = s;
    }
}

// ---------------------------------------------------------------------------
// K3: finalize loss at out[NTOK*9] from 1024 x 16 partials (= 4096 float4).
// 256 threads; thread t loads 16 independent float4 (p4[i*256 + t], i=0..15,
// coalesced, all in flight), accumulating stats [4*(t&3) .. 4*(t&3)+3] over
// rows i*64 + (t>>2). LDS reduce across the 64 threads per stat group; final
// 16-lane shuffle product (same proven math as R5/R6).
// ---------------------------------------------------------------------------
__global__ __launch_bounds__(256) void finalize_kernel(
    const float* __restrict__ partials, float* __restrict__ out)
{
    __shared__ float lds[256 * 4];
    const int t = threadIdx.x;
    const float4* p4 = (const float4*)partials;

    float4 a = make_float4(0.f, 0.f, 0.f, 0.f);
    #pragma unroll
    for (int i = 0; i < 16; ++i) {            // 16 independent float4 loads
        float4 v = p4[i * 256 + t];
        a.x += v.x; a.y += v.y; a.z += v.z; a.w += v.w;
    }
    *(float4*)&lds[t * 4] = a;
    __syncthreads();

    if (t < 16) {
        const int c = t >> 2, m = t & 3;      // stat t = 4c + m
        float tot = 0.f;
        #pragma unroll
        for (int q = 0; q < 64; ++q)
            tot += lds[(q * 4 + c) * 4 + m];
        // lanes 0..15 hold totals for the 16 stats
        const float invN = 1.0f / (float)NTOK;
        float partner = __shfl_xor(tot, 8);   // pairs sum <-> sumsq
        float prod = (tot * invN) * (partner * invN);
        prod += __shfl_xor(prod, 1);
        prod += __shfl_xor(prod, 2);
        prod += __shfl_xor(prod, 4);
        if (t == 0)
            out[(size_t)NTOK * 9] = prod * 64.0f;   // * E^2
    }
}

extern "C" void kernel_launch(void* const* d_in, const int* in_sizes, int n_in,
                              void* d_out, int out_size, void* d_ws, size_t ws_size,
                              hipStream_t stream) {
    const float* x     = (const float*)d_in[0];
    const float* W     = (const float*)d_in[1];
    const float* noise = (const float*)d_in[2];
    float* out = (float*)d_out;
    float* partials = (float*)d_ws;   // 1024*16 floats = 64 KB

    fused_kernel<<<K1_NB, 256, 0, stream>>>(x, W, noise, out, partials);
    finalize_kernel<<<1, 256, 0, stream>>>(partials, out);
}